// Round 1
// baseline (288.982 us; speedup 1.0000x reference)
//
#include <hip/hip_runtime.h>

#define N_VERT 35709
#define N_FACE 70789
#define NB 32
#define M3 (3*N_VERT)        // 107127

// ---- workspace layout (float offsets), vertex-major batch-inner ----
#define WS_FS4X  ((size_t)0)                          // [N_VERT][32][4]
#define WS_FN4X  (WS_FS4X + (size_t)N_VERT*128)       // [N_FACE+1][32][4] (zero row at N_FACE)
#define WS_CPAD  (WS_FN4X + (size_t)(N_FACE+1)*128)   // [32][256]
#define WS_ROT   (WS_CPAD + (size_t)NB*256)           // [32][9]
#define WS_TRE   (WS_ROT + (size_t)NB*9)              // [32][3]
#define WS_G     (WS_TRE + (size_t)NB*3)              // [32][27]
#define WS_MEAN  (WS_G + (size_t)NB*27)               // [3] atomic sums

// ---- output layout (float offsets) ----
#define FC_OFF   ((size_t)0)
#define LM_OFF   ((size_t)NB*M3)                      // 3428064
#define FST_OFF  (LM_OFF + (size_t)NB*68*2)

// ---- SH constants ----
#define A0C0 0.88622692545275801f
#define A1C1 1.77245385090551603f
#define A2C2 2.42703239430f
#define Y6C  0.70062393935f
#define Y8C  1.21351619715f

// ======================= Stage A1: meanshape partial sums =======================
__global__ void __launch_bounds__(256) face3d_stageA1(
    const float* __restrict__ ms, float* __restrict__ ws) {
  float s0=0.f, s1=0.f, s2=0.f;
  for (int v = blockIdx.x*256 + threadIdx.x; v < N_VERT; v += gridDim.x*256) {
    s0 += ms[3*v+0]; s1 += ms[3*v+1]; s2 += ms[3*v+2];
  }
  #pragma unroll
  for (int off = 32; off > 0; off >>= 1) {
    s0 += __shfl_down(s0, off);
    s1 += __shfl_down(s1, off);
    s2 += __shfl_down(s2, off);
  }
  if ((threadIdx.x & 63) == 0) {
    atomicAdd(&ws[WS_MEAN+0], s0);
    atomicAdd(&ws[WS_MEAN+1], s1);
    atomicAdd(&ws[WS_MEAN+2], s2);
  }
}

// ======================= Stage A2: per-batch constants =======================
__global__ void __launch_bounds__(256) face3d_stageA2(
    const float* __restrict__ coeff, float* __restrict__ ws) {
  int t = threadIdx.x;
  float m0 = ws[WS_MEAN+0]*(1.0f/N_VERT);
  float m1 = ws[WS_MEAN+1]*(1.0f/N_VERT);
  float m2 = ws[WS_MEAN+2]*(1.0f/N_VERT);
  for (int idx = t; idx < NB*256; idx += 256) {
    int b = idx >> 8, k = idx & 255;
    ws[WS_CPAD + idx] = (k < 244) ? coeff[b*277 + k] : 0.0f;
  }
  for (int idx = t; idx < NB*27; idx += 256) {
    int b = idx / 27, k = idx - b*27;
    ws[WS_G + idx] = coeff[b*277 + 247 + k] + (((k % 9) == 0) ? 0.8f : 0.0f);
  }
  if (t < NB) {
    int b = t;
    float ax = coeff[b*277+244], ay = coeff[b*277+245], az = coeff[b*277+246];
    float cx=cosf(ax), sx=sinf(ax);
    float cy=cosf(ay), sy=sinf(ay);
    float cz=cosf(az), sz=sinf(az);
    float T00=cz*cy, T01=-sz, T02=cz*sy;
    float T10=sz*cy, T11=cz,  T12=sz*sy;
    float T20=-sy,   T21=0.f, T22=cy;
    float R[3][3];
    R[0][0]=T00; R[0][1]=T01*cx+T02*sx; R[0][2]=-T01*sx+T02*cx;
    R[1][0]=T10; R[1][1]=T11*cx+T12*sx; R[1][2]=-T11*sx+T12*cx;
    R[2][0]=T20; R[2][1]=T21*cx+T22*sx; R[2][2]=-T21*sx+T22*cx;
    float rot[3][3];
    #pragma unroll
    for (int c=0;c<3;c++)
      #pragma unroll
      for (int j=0;j<3;j++)
        rot[c][j] = R[j][c];
    #pragma unroll
    for (int c=0;c<3;c++)
      #pragma unroll
      for (int j=0;j<3;j++)
        ws[WS_ROT + b*9 + c*3 + j] = rot[c][j];
    #pragma unroll
    for (int j=0;j<3;j++)
      ws[WS_TRE + b*3 + j] = coeff[b*277+274+j]
        - (m0*rot[0][j] + m1*rot[1][j] + m2*rot[2][j]);
  }
}

// ======================= Stage B: GEMMs, register-tiled 4 rows x 8 batches =======================
// Grid: 2*ceil(M3/256) blocks. Even blocks: fs = idB*id_c + exB*ex_c + meanshape.
// Odd blocks: tex = texB*tex_c + meantex.
// Per block: 256 rows x 32 batches. 4 waves; wave w handles batches [8w, 8w+8).
// Thread: rows {lane, lane+64, lane+128, lane+192} (interleaved), 8 batches -> acc[4][8].
// K tiled in slabs of 20 floats (5 float4). LDS layout per buffer:
//   A: [256 rows][KT4 f4] linear (pitch 5 -> (5*lane+s4)%8 full quad-bank perm, conflict-free)
//   W: [32 b][KT4 f4] appended at 256*KT4 (broadcast reads, free)
// Staged via global_load_lds width=16, double-buffered with counted vmcnt + raw s_barrier.

__device__ __forceinline__ void gload16(const void* g, void* l) {
  __builtin_amdgcn_global_load_lds((const __attribute__((address_space(1))) void*)g,
                                   (__attribute__((address_space(3))) void*)l, 16, 0, 0);
}

#define B_SYNC() do { __builtin_amdgcn_sched_barrier(0); \
                      __builtin_amdgcn_s_barrier(); \
                      __builtin_amdgcn_sched_barrier(0); } while (0)
#define B_WAIT(N) do { __builtin_amdgcn_sched_barrier(0); \
                       asm volatile("s_waitcnt vmcnt(" #N ")"); \
                       B_SYNC(); } while (0)

template<int KT4>
__device__ __forceinline__ void stageB_stage(const float* __restrict__ A, int K4,
                                             int gk4, const float* __restrict__ cpad,
                                             int wk4, int r0, int t,
                                             float4* __restrict__ buf) {
  // A part: 256*KT4 float4, i = p*256+t maps to (row,s4) = (i/KT4, i%KT4) == linear index i
  #pragma unroll
  for (int p = 0; p < KT4; ++p) {
    int i = p*256 + t;
    int row = i / KT4;
    int s4 = i - row*KT4;
    int gr = r0 + row; gr = (gr < M3) ? gr : (M3-1);
    gload16(A + ((size_t)gr*K4 + gk4 + s4)*4, buf + i);
  }
  // W part: 32*KT4 float4 (padded to 256 lanes so every wave issues the same count)
  {
    int b = t / KT4;
    int s4 = t - b*KT4;
    if (b >= NB) { b = NB-1; s4 = KT4-1; }
    gload16(cpad + ((size_t)b*64 + wk4 + s4)*4, buf + 256*KT4 + t);
  }
}

template<int KT4>
__device__ __forceinline__ void stageB_compute(const float4* __restrict__ buf,
                                               int bg8, int lane, float acc[4][8]) {
  const float4* __restrict__ Wl = buf + 256*KT4;
  #pragma unroll
  for (int s4 = 0; s4 < KT4; ++s4) {
    float4 a0 = buf[(lane      )*KT4 + s4];
    float4 a1 = buf[(lane +  64)*KT4 + s4];
    float4 a2 = buf[(lane + 128)*KT4 + s4];
    float4 a3 = buf[(lane + 192)*KT4 + s4];
    #pragma unroll
    for (int bb = 0; bb < 8; ++bb) {
      float4 w = Wl[(bg8 + bb)*KT4 + s4];
      acc[0][bb] = fmaf(a0.w, w.w, fmaf(a0.z, w.z, fmaf(a0.y, w.y, fmaf(a0.x, w.x, acc[0][bb]))));
      acc[1][bb] = fmaf(a1.w, w.w, fmaf(a1.z, w.z, fmaf(a1.y, w.y, fmaf(a1.x, w.x, acc[1][bb]))));
      acc[2][bb] = fmaf(a2.w, w.w, fmaf(a2.z, w.z, fmaf(a2.y, w.y, fmaf(a2.x, w.x, acc[2][bb]))));
      acc[3][bb] = fmaf(a3.w, w.w, fmaf(a3.z, w.z, fmaf(a3.y, w.y, fmaf(a3.x, w.x, acc[3][bb]))));
    }
  }
}

__global__ void __launch_bounds__(256) face3d_stageB(
    const float* __restrict__ idB, const float* __restrict__ exB,
    const float* __restrict__ texB, const float* __restrict__ meanshape,
    const float* __restrict__ meantex, const float* __restrict__ cpad,
    float* __restrict__ fs4x, float* __restrict__ texOut) {
  __shared__ float4 lds[2][1536];   // 48 KB -> 3 blocks/CU
  int t = threadIdx.x;
  int lane = t & 63;
  int bg8 = (t >> 6) << 3;          // wave's batch base (wave-uniform)
  int bid = blockIdx.x;
  int r0 = (bid >> 1) * 256;

  float acc[4][8];
  #pragma unroll
  for (int j = 0; j < 4; ++j)
    #pragma unroll
    for (int bb = 0; bb < 8; ++bb) acc[j][bb] = 0.f;

  float4* buf0 = &lds[0][0];
  float4* buf1 = &lds[1][0];

  if ((bid & 1) == 0) {
    // ---- fs: id (K=80, 4 tiles of 20f) + ex (K=64, 3 tiles of 20f + 1 tile of 4f) ----
    stageB_stage<5>(idB, 20, 0, cpad, 0, r0, t, buf0);     // T0
    #pragma unroll 1
    for (int tt = 0; tt < 7; ++tt) {
      int nt = tt + 1;
      float4* nb = (tt & 1) ? buf0 : buf1;                 // buf[nt&1]
      if (nt < 7) {
        const float* An = (nt < 4) ? idB : exB;
        int K4n = (nt < 4) ? 20 : 16;
        int g4n = (nt < 4) ? nt*5 : (nt-4)*5;
        stageB_stage<5>(An, K4n, g4n, cpad, nt*5, r0, t, nb);
        B_WAIT(6);                                         // tile tt's 6 loads done
      } else {
        stageB_stage<1>(exB, 16, 15, cpad, 35, r0, t, nb); // ex tail: floats 60..63 -> cpad 140..143
        B_WAIT(2);
      }
      stageB_compute<5>((tt & 1) ? buf1 : buf0, bg8, lane, acc);
      B_SYNC();                                            // all waves done reading this buffer
    }
    B_WAIT(0);
    stageB_compute<1>(buf1, bg8, lane, acc);               // T7 in buf[7&1]
    // epilogue: + meanshape, scatter to fs4x [v][32][4]
    #pragma unroll
    for (int j = 0; j < 4; ++j) {
      int r = r0 + lane + 64*j;
      if (r < M3) {
        float ms = meanshape[r];
        int v = r / 3;
        int c = r - 3*v;
        float* dst = fs4x + (size_t)v*128 + c;
        #pragma unroll
        for (int bb = 0; bb < 8; ++bb)
          dst[(bg8 + bb)*4] = acc[j][bb] + ms;
      }
    }
  } else {
    // ---- tex: K=100, 5 tiles of 20f; cpad floats 144..243 (f4 36..60) ----
    stageB_stage<5>(texB, 25, 0, cpad, 36, r0, t, buf0);
    #pragma unroll 1
    for (int tt = 0; tt < 5; ++tt) {
      if (tt < 4) {
        stageB_stage<5>(texB, 25, (tt+1)*5, cpad, 36 + (tt+1)*5, r0, t,
                        (tt & 1) ? buf0 : buf1);
        B_WAIT(6);
      } else {
        B_WAIT(0);
      }
      stageB_compute<5>((tt & 1) ? buf1 : buf0, bg8, lane, acc);
      if (tt < 4) B_SYNC();
    }
    // epilogue: + meantex, coalesced per batch
    #pragma unroll
    for (int j = 0; j < 4; ++j) {
      int r = r0 + lane + 64*j;
      if (r < M3) {
        float mt = meantex[r];
        #pragma unroll
        for (int bb = 0; bb < 8; ++bb)
          texOut[(size_t)(bg8 + bb)*M3 + r] = acc[j][bb] + mt;
      }
    }
  }
}

// ======================= Stage C: face normals (8 faces x 32 batches / block) =======================
__global__ void __launch_bounds__(256) face3d_stageC(
    const int* __restrict__ face_buf, const float* __restrict__ fs4x,
    float* __restrict__ fn4x) {
  int t = threadIdx.x;
  int b = t & 31, fi = t >> 5;
  int f = blockIdx.x*8 + fi;
  if (f > N_FACE) return;
  float4* o = (float4*)(fn4x + ((size_t)f*32 + b)*4);
  if (f == N_FACE) { *o = make_float4(0.f,0.f,0.f,0.f); return; }
  int i0 = face_buf[f*3+0];
  int i1 = face_buf[f*3+1];
  int i2 = face_buf[f*3+2];
  float4 p1 = *(const float4*)(fs4x + ((size_t)i0*32 + b)*4);
  float4 p2 = *(const float4*)(fs4x + ((size_t)i1*32 + b)*4);
  float4 p3 = *(const float4*)(fs4x + ((size_t)i2*32 + b)*4);
  float e1x = p1.x-p2.x, e1y = p1.y-p2.y, e1z = p1.z-p2.z;
  float e2x = p2.x-p3.x, e2y = p2.y-p3.y, e2z = p2.z-p3.z;
  float nx = e1y*e2z - e1z*e2y;
  float ny = e1z*e2x - e1x*e2z;
  float nz = e1x*e2y - e1y*e2x;
  float inv = 1.0f / fmaxf(sqrtf(nx*nx + ny*ny + nz*nz), 1e-12f);
  *o = make_float4(nx*inv, ny*inv, nz*inv, 0.f);
}

// ======================= Stage D: vertex normals + lighting + fst (+landmarks) =======================
__global__ void __launch_bounds__(256) face3d_stageD(
    const int* __restrict__ point_buf, const int* __restrict__ keypoints,
    const float* __restrict__ fs4x, const float* __restrict__ fn4x,
    const float* __restrict__ rotAll, const float* __restrict__ treAll,
    const float* __restrict__ gAll, float* __restrict__ out) {
  const int mainBlocks = (N_VERT + 7)/8;   // 4464
  int bid = blockIdx.x;
  int t = threadIdx.x;
  if (bid < mainBlocks) {
    __shared__ float rotL[NB*9];
    __shared__ float treL[NB*3];
    __shared__ float gL[NB*27];
    __shared__ float fstL[NB*33];   // [b]: stride 33, [w*4+c]
    __shared__ float LL[NB*33];
    if (t < NB*9)  rotL[t] = rotAll[t];
    if (t < NB*3)  treL[t] = treAll[t];
    for (int i = t; i < NB*27; i += 256) gL[i] = gAll[i];
    __syncthreads();
    int b = t & 31, vi = t >> 5;
    int v0 = bid*8;
    int v = v0 + vi;
    if (v < N_VERT) {
      const int4 pb0 = *(const int4*)(point_buf + (size_t)v*8);
      const int4 pb1 = *(const int4*)(point_buf + (size_t)v*8 + 4);
      float4 g0 = *(const float4*)(fn4x + ((size_t)pb0.x*32 + b)*4);
      float4 g1 = *(const float4*)(fn4x + ((size_t)pb0.y*32 + b)*4);
      float4 g2 = *(const float4*)(fn4x + ((size_t)pb0.z*32 + b)*4);
      float4 g3 = *(const float4*)(fn4x + ((size_t)pb0.w*32 + b)*4);
      float4 g4 = *(const float4*)(fn4x + ((size_t)pb1.x*32 + b)*4);
      float4 g5 = *(const float4*)(fn4x + ((size_t)pb1.y*32 + b)*4);
      float4 g6 = *(const float4*)(fn4x + ((size_t)pb1.z*32 + b)*4);
      float4 g7 = *(const float4*)(fn4x + ((size_t)pb1.w*32 + b)*4);
      float sx = ((g0.x+g1.x)+(g2.x+g3.x)) + ((g4.x+g5.x)+(g6.x+g7.x));
      float sy = ((g0.y+g1.y)+(g2.y+g3.y)) + ((g4.y+g5.y)+(g6.y+g7.y));
      float sz = ((g0.z+g1.z)+(g2.z+g3.z)) + ((g4.z+g5.z)+(g6.z+g7.z));
      float inv = 1.0f / fmaxf(sqrtf(sx*sx + sy*sy + sz*sz), 1e-12f);
      float n0 = sx*inv, n1 = sy*inv, n2 = sz*inv;
      const float* rot = rotL + b*9;
      float r00=rot[0], r01=rot[1], r02=rot[2];
      float r10=rot[3], r11=rot[4], r12=rot[5];
      float r20=rot[6], r21=rot[7], r22=rot[8];
      float nx = n0*r00 + n1*r10 + n2*r20;
      float ny = n0*r01 + n1*r11 + n2*r21;
      float nz = n0*r02 + n1*r12 + n2*r22;
      float Y1 = -A1C1*ny;
      float Y2 =  A1C1*nz;
      float Y3 = -A1C1*nx;
      float Y4 =  A2C2*nx*ny;
      float Y5 = -A2C2*ny*nz;
      float Y6 =  Y6C*(3.f*nz*nz - 1.f);
      float Y7 = -A2C2*nx*nz;
      float Y8 =  Y8C*(nx*nx - ny*ny);
      const float* g = gL + b*27;
      #pragma unroll
      for (int c = 0; c < 3; ++c) {
        const float* gc = g + c*9;
        float Lc = A0C0*gc[0] + Y1*gc[1] + Y2*gc[2] + Y3*gc[3] + Y4*gc[4]
                 + Y5*gc[5] + Y6*gc[6] + Y7*gc[7] + Y8*gc[8];
        LL[b*33 + vi*4 + c] = Lc;
      }
      float4 fsv = *(const float4*)(fs4x + ((size_t)v*32 + b)*4);
      const float* tre = treL + b*3;
      fstL[b*33 + vi*4 + 0] = fsv.x*r00 + fsv.y*r10 + fsv.z*r20 + tre[0];
      fstL[b*33 + vi*4 + 1] = fsv.x*r01 + fsv.y*r11 + fsv.z*r21 + tre[1];
      fstL[b*33 + vi*4 + 2] = fsv.x*r02 + fsv.y*r12 + fsv.z*r22 + tre[2];
    }
    __syncthreads();
    // phase 2: transpose out. t -> b2 = t>>3 (32), w = t&7 (8 vertices)
    int b2 = t >> 3, w = t & 7;
    if (v0 + w < N_VERT) {
      size_t obase = (size_t)b2*M3 + (size_t)(v0 + w)*3;
      float f0 = fstL[b2*33 + w*4 + 0];
      float f1 = fstL[b2*33 + w*4 + 1];
      float f2 = fstL[b2*33 + w*4 + 2];
      out[FST_OFF + obase + 0] = f0;
      out[FST_OFF + obase + 1] = f1;
      out[FST_OFF + obase + 2] = f2;
      float l0 = LL[b2*33 + w*4 + 0];
      float l1 = LL[b2*33 + w*4 + 1];
      float l2 = LL[b2*33 + w*4 + 2];
      float t0 = out[FC_OFF + obase + 0];
      float t1 = out[FC_OFF + obase + 1];
      float t2 = out[FC_OFF + obase + 2];
      out[FC_OFF + obase + 0] = t0*l0;
      out[FC_OFF + obase + 1] = t1*l1;
      out[FC_OFF + obase + 2] = t2*l2;
    }
  } else {
    int idx = (bid - mainBlocks)*256 + t;
    if (idx >= NB*68) return;
    int b = idx & 31, j = idx >> 5;
    int kp = keypoints[j];
    const float* rot = rotAll + b*9;
    const float* tre = treAll + b*3;
    float4 fsv = *(const float4*)(fs4x + ((size_t)kp*32 + b)*4);
    float o0 = fsv.x*rot[0] + fsv.y*rot[3] + fsv.z*rot[6] + tre[0];
    float o1 = fsv.x*rot[1] + fsv.y*rot[4] + fsv.z*rot[7] + tre[1];
    float o2 = fsv.x*rot[2] + fsv.y*rot[5] + fsv.z*rot[8] + tre[2];
    float zc = 10.0f - o2;
    float axv = 1015.0f*o0 + 112.0f*zc;
    float ayv = 1015.0f*o1 + 112.0f*zc;
    out[LM_OFF + (size_t)b*136 + (size_t)j*2 + 0] = axv/zc;
    out[LM_OFF + (size_t)b*136 + (size_t)j*2 + 1] = ayv/zc;
  }
}

// ======================= launch =======================
extern "C" void kernel_launch(void* const* d_in, const int* in_sizes, int n_in,
                              void* d_out, int out_size, void* d_ws, size_t ws_size,
                              hipStream_t stream) {
  const float* coeff     = (const float*)d_in[0];
  const float* idB       = (const float*)d_in[1];
  const float* exB       = (const float*)d_in[2];
  const float* texB      = (const float*)d_in[3];
  const float* meanshape = (const float*)d_in[4];
  const float* meantex   = (const float*)d_in[5];
  const int*   face_buf  = (const int*)d_in[6];
  const int*   point_buf = (const int*)d_in[7];
  const int*   keypoints = (const int*)d_in[8];
  float* out = (float*)d_out;
  float* ws  = (float*)d_ws;

  hipMemsetAsync((char*)d_ws + WS_MEAN*sizeof(float), 0, 3*sizeof(float), stream);

  hipLaunchKernelGGL(face3d_stageA1, dim3(56), dim3(256), 0, stream, meanshape, ws);
  hipLaunchKernelGGL(face3d_stageA2, dim3(1), dim3(256), 0, stream, coeff, ws);

  int gridB = 2 * ((M3 + 255)/256);      // 838: even=fs, odd=tex
  hipLaunchKernelGGL(face3d_stageB, dim3(gridB), dim3(256), 0, stream,
                     idB, exB, texB, meanshape, meantex,
                     ws + WS_CPAD, ws + WS_FS4X, out + FC_OFF);

  int gridC = (N_FACE + 1 + 7)/8;        // 8849
  hipLaunchKernelGGL(face3d_stageC, dim3(gridC), dim3(256), 0, stream,
                     face_buf, ws + WS_FS4X, ws + WS_FN4X);

  int mainBlocks = (N_VERT + 7)/8;       // 4464
  int lmBlocks   = (NB*68 + 255)/256;    // 9
  hipLaunchKernelGGL(face3d_stageD, dim3(mainBlocks + lmBlocks), dim3(256), 0, stream,
                     point_buf, keypoints, ws + WS_FS4X, ws + WS_FN4X,
                     ws + WS_ROT, ws + WS_TRE, ws + WS_G, out);
}